// Round 8
// baseline (1868.914 us; speedup 1.0000x reference)
//
#include <hip/hip_runtime.h>
#include <cfloat>

// Farthest Point Sampling: B=32, N=200000, M=128.
// Zero-barrier decentralized design: 8 blocks/batch x 1024 threads, 1 block/CU
// (LDS-forced), XCD-local batches. Per thread 25 points: 13 xyz in VGPRs +
// 12 xyz in LDS float4 (thread-private columns); md[25] in VGPRs.
// Each WAVE publishes its candidate tag (val|idx|iter in one u64, relaxed
// agent atomics -> no buffer_inv) to the batch's 128-slot group in the local
// XCD L2; every wave polls all 128 slots, reduces, and fetches the winner's
// coords itself. No __syncthreads anywhere in the loop.
#define B_    32
#define N_    200000
#define M_    128
#define BPB   8                    // blocks per batch
#define T_    1024                 // threads per block
#define NW    16                   // waves per block
#define PV    13                   // points with xyz in VGPRs
#define PL    12                   // points with xyz in LDS (3 float4 groups)
#define PT    (PV + PL)            // 25; 8*1024*25 = 204800 >= N
#define CHUNK (T_ * PT)            // 25600 points per block

#define SPIN_CAP (1 << 20)         // safety valve: never hang the container

__global__ __launch_bounds__(T_, 4)
void fps_kernel(const float* __restrict__ pts, int* __restrict__ out,
                unsigned long long* __restrict__ tags) {
  const int tid = threadIdx.x;
  const int bid = blockIdx.x;
  // XCD-local batches: blocks round-robin XCDs by bid&7 (measured m09).
  // All 8 blocks of a batch -> one XCD; the batch's 2.4MB of points fits that
  // XCD's 4MB L2 -> tag exchange AND coord fetches stay L2-local.
  const int xcd = bid & 7;
  const int sl8 = bid >> 3;                  // 0..31 within this XCD
  const int b   = ((sl8 >> 3) << 3) | xcd;   // batch (b&7 == xcd)
  const int c   = sl8 & 7;                   // chunk within batch
  const int wave = tid >> 6;
  const int lane = tid & 63;

  const float* __restrict__ P = pts + (size_t)b * (size_t)(N_ * 3);
  const int base = c * CHUNK + tid;          // this thread's j=0 global index

  // 3 arrays x [3][1024] float4 = 144 KiB -> exactly 1 block/CU.
  // Thread-private columns, stride-16B b128 pattern: conflict-free, and since
  // no thread reads another's column, NO barrier is ever needed.
  __shared__ float4 sX[3][T_], sY[3][T_], sZ[3][T_];

  // ---- one-time load ----
  float vx[PV], vy[PV], vz[PV], md[PT];
  #pragma unroll
  for (int j = 0; j < PV; ++j) {
    int g = base + j * T_;
    if (g < N_) {
      const float* p = P + (size_t)g * 3;
      vx[j] = p[0]; vy[j] = p[1]; vz[j] = p[2];
      md[j] = __builtin_huge_valf();
    } else { vx[j] = vy[j] = vz[j] = 0.f; md[j] = -FLT_MAX; }
  }
  #pragma unroll
  for (int grp = 0; grp < 3; ++grp) {
    float qx[4], qy[4], qz[4];
    #pragma unroll
    for (int q = 0; q < 4; ++q) {
      int j = PV + grp * 4 + q;
      int g = base + j * T_;
      if (g < N_) {
        const float* p = P + (size_t)g * 3;
        qx[q] = p[0]; qy[q] = p[1]; qz[q] = p[2];
        md[j] = __builtin_huge_valf();
      } else { qx[q] = qy[q] = qz[q] = 0.f; md[j] = -FLT_MAX; }
    }
    sX[grp][tid] = make_float4(qx[0], qx[1], qx[2], qx[3]);
    sY[grp][tid] = make_float4(qy[0], qy[1], qy[2], qy[3]);
    sZ[grp][tid] = make_float4(qz[0], qz[1], qz[2], qz[3]);
  }

  float cx = P[0], cy = P[1], cz = P[2];     // initial center = point 0
  if (c == 0 && tid == 0) out[b * M_ + 0] = 0;

  for (int it = 1; it < M_; ++it) {
    // ---- distance + running-min + 4-chain argmax (j tracked, 5 bits) ----
    // No exclusion select: the chosen point's self-distance is exactly 0
    // (coords bit-exact), min(md,0)=0 never beats any positive min-dist, so
    // the argmax sequence matches the reference (proven r5-r7).
    float bv[4] = {-FLT_MAX, -FLT_MAX, -FLT_MAX, -FLT_MAX};
    int   bj[4] = {0x7FFF, 0x7FFF, 0x7FFF, 0x7FFF};

    #pragma unroll
    for (int j = 0; j < PV; ++j) {
      float dx = __fsub_rn(vx[j], cx);
      float dy = __fsub_rn(vy[j], cy);
      float dz = __fsub_rn(vz[j], cz);
      // numpy: ((dx*dx + dy*dy) + dz*dz), rn, no FMA contraction
      float d  = __fadd_rn(__fadd_rn(__fmul_rn(dx, dx), __fmul_rn(dy, dy)),
                           __fmul_rn(dz, dz));
      float m  = fminf(md[j], d);            // np.minimum
      md[j] = m;
      const int q = j & 3;
      bool take = m > bv[q];                 // ascending j: strict >
      bv[q] = take ? m : bv[q];
      bj[q] = take ? j : bj[q];
    }
    #pragma unroll
    for (int grp = 0; grp < 3; ++grp) {
      float4 qx = sX[grp][tid], qy = sY[grp][tid], qz = sZ[grp][tid];
      #pragma unroll
      for (int q4 = 0; q4 < 4; ++q4) {
        const int j = PV + grp * 4 + q4;
        float X = (q4 == 0) ? qx.x : (q4 == 1) ? qx.y : (q4 == 2) ? qx.z : qx.w;
        float Y = (q4 == 0) ? qy.x : (q4 == 1) ? qy.y : (q4 == 2) ? qy.z : qy.w;
        float Z = (q4 == 0) ? qz.x : (q4 == 1) ? qz.y : (q4 == 2) ? qz.z : qz.w;
        float dx = __fsub_rn(X, cx);
        float dy = __fsub_rn(Y, cy);
        float dz = __fsub_rn(Z, cz);
        float d  = __fadd_rn(__fadd_rn(__fmul_rn(dx, dx), __fmul_rn(dy, dy)),
                             __fmul_rn(dz, dz));
        float m  = fminf(md[j], d);
        md[j] = m;
        const int q = j & 3;
        bool take = m > bv[q];
        bv[q] = take ? m : bv[q];
        bj[q] = take ? j : bj[q];
      }
    }
    // merge 4 chains (tie -> smaller j = smaller global idx = first occurrence)
    float tv = bv[0]; int tj = bj[0];
    #pragma unroll
    for (int q = 1; q < 4; ++q) {
      bool take = (bv[q] > tv) || (bv[q] == tv && bj[q] < tj);
      tv = take ? bv[q] : tv;
      tj = take ? bj[q] : tj;
    }
    int ti = base + tj * T_;                 // reconstruct global idx once

    // ---- wave reduction (64 lanes) ----
    #pragma unroll
    for (int o = 32; o > 0; o >>= 1) {
      float ov = __shfl_xor(tv, o);
      int   oi = __shfl_xor(ti, o);
      bool take = (ov > tv) || (ov == tv && oi < ti);
      tv = take ? ov : tv;
      ti = take ? oi : ti;
    }

    // ---- publish this wave's candidate (one u64 tag, relaxed agent) ----
    // 128 slots per batch per parity: slot = c*16 + wave.
    unsigned long long* grp = tags + (((size_t)(b << 1) + (it & 1)) << 7);
    if (lane == 0) {
      unsigned long long tg =
          ((unsigned long long)__float_as_uint(tv) << 32) |
          ((unsigned long long)(unsigned)ti << 7) | (unsigned)it;
      __hip_atomic_store(grp + ((c << 4) | wave), tg,
                         __ATOMIC_RELAXED, __HIP_MEMORY_SCOPE_AGENT);
    }

    // ---- every wave polls all 128 slots (lane l -> slots l, l+64) ----
    unsigned long long t0 = 0, t1 = 0;
    {
      int sp = 0;
      for (;;) {
        t0 = __hip_atomic_load(grp + lane,      __ATOMIC_RELAXED, __HIP_MEMORY_SCOPE_AGENT);
        t1 = __hip_atomic_load(grp + lane + 64, __ATOMIC_RELAXED, __HIP_MEMORY_SCOPE_AGENT);
        bool ok = ((t0 & 127ull) == (unsigned long long)(unsigned)it) &&
                  ((t1 & 127ull) == (unsigned long long)(unsigned)it);
        if (__all(ok)) break;
        if (++sp > SPIN_CAP) break;          // wrong answer >> dead container
        __builtin_amdgcn_s_sleep(1);
      }
    }
    // merge the two slots, then 6-stage butterfly -> global winner (all lanes)
    float v0 = __uint_as_float((unsigned)(t0 >> 32));
    int   i0 = (int)((t0 >> 7) & 0x3FFFF);
    float v1 = __uint_as_float((unsigned)(t1 >> 32));
    int   i1 = (int)((t1 >> 7) & 0x3FFFF);
    bool tk = (v1 > v0) || (v1 == v0 && i1 < i0);
    float cv = tk ? v1 : v0;
    int   ci = tk ? i1 : i0;
    #pragma unroll
    for (int o = 32; o > 0; o >>= 1) {
      float ov = __shfl_xor(cv, o);
      int   oi = __shfl_xor(ci, o);
      bool take = (ov > cv) || (ov == cv && oi < ci);
      cv = take ? ov : cv;
      ci = take ? oi : ci;
    }

    if (c == 0 && tid == 0) out[b * M_ + it] = ci;   // fire-and-forget

    // winner coords: read-only P, XCD-L2-resident -> ~200cy broadcast load.
    const float* pw = P + (size_t)ci * 3;
    cx = pw[0]; cy = pw[1]; cz = pw[2];
  }
}

extern "C" void kernel_launch(void* const* d_in, const int* in_sizes, int n_in,
                              void* d_out, int out_size, void* d_ws, size_t ws_size,
                              hipStream_t stream) {
  const float*        pts  = (const float*)d_in[0];
  int*                out  = (int*)d_out;
  unsigned long long* tags = (unsigned long long*)d_ws;

  // zero tag slots each launch (tag 0 never matches it>=1); capture-safe
  hipMemsetAsync(d_ws, 0, (size_t)B_ * 2 * 128 * sizeof(unsigned long long), stream);

  // 144 KiB LDS/block -> 1 block/CU; grid == 256 == CU count -> co-resident.
  fps_kernel<<<dim3(B_ * BPB), dim3(T_), 0, stream>>>(pts, out, tags);
}

// Round 9
// 1222.474 us; speedup vs baseline: 1.5288x; 1.5288x over previous
//
#include <hip/hip_runtime.h>
#include <cfloat>

// Farthest Point Sampling: B=32, N=200000, M=128.
// Zero-barrier decentralized design (r8) + LDS-residency fences (r8 bugfix):
// without barriers the compiler store-forwarded the LDS staging into repeated
// global re-loads and deleted the arrays (r8: LDS_Block_Size=0, 3.5x slower).
// asm memory fences make forwarding illegal; LDS stays allocated -> 1 block/CU.
// 8 blocks/batch x 1024 threads; per thread 25 points: 13 xyz in VGPRs +
// 12 xyz in LDS float4 (thread-private columns); md[25] in VGPRs.
// Each WAVE publishes its candidate tag (val|idx|iter in one u64, relaxed
// agent atomics -> no buffer_inv) to the batch's 128-slot group in the local
// XCD L2; every wave polls all 128 slots, reduces, and fetches the winner's
// coords itself. No __syncthreads in the loop.
#define B_    32
#define N_    200000
#define M_    128
#define BPB   8                    // blocks per batch
#define T_    1024                 // threads per block
#define NW    16                   // waves per block
#define PV    13                   // points with xyz in VGPRs
#define PL    12                   // points with xyz in LDS (3 float4 groups)
#define PT    (PV + PL)            // 25; 8*1024*25 = 204800 >= N
#define CHUNK (T_ * PT)            // 25600 points per block

#define SPIN_CAP (1 << 20)         // safety valve: never hang the container

__global__ __launch_bounds__(T_, 4)
void fps_kernel(const float* __restrict__ pts, int* __restrict__ out,
                unsigned long long* __restrict__ tags) {
  const int tid = threadIdx.x;
  const int bid = blockIdx.x;
  // XCD-local batches: blocks round-robin XCDs by bid&7 (measured m09).
  // All 8 blocks of a batch -> one XCD; the batch's 2.4MB of points fits that
  // XCD's 4MB L2 -> tag exchange AND coord fetches stay L2-local.
  const int xcd = bid & 7;
  const int sl8 = bid >> 3;                  // 0..31 within this XCD
  const int b   = ((sl8 >> 3) << 3) | xcd;   // batch (b&7 == xcd)
  const int c   = sl8 & 7;                   // chunk within batch
  const int wave = tid >> 6;
  const int lane = tid & 63;

  const float* __restrict__ P = pts + (size_t)b * (size_t)(N_ * 3);
  const int base = c * CHUNK + tid;          // this thread's j=0 global index

  // 3 arrays x [3][1024] float4 = 144 KiB -> exactly 1 block/CU.
  // Thread-private columns, stride-16B b128 pattern: conflict-free; no thread
  // reads another's column, so no barrier is semantically required.
  __shared__ float4 sX[3][T_], sY[3][T_], sZ[3][T_];

  // ---- one-time load ----
  float vx[PV], vy[PV], vz[PV], md[PT];
  #pragma unroll
  for (int j = 0; j < PV; ++j) {
    int g = base + j * T_;
    if (g < N_) {
      const float* p = P + (size_t)g * 3;
      vx[j] = p[0]; vy[j] = p[1]; vz[j] = p[2];
      md[j] = __builtin_huge_valf();
    } else { vx[j] = vy[j] = vz[j] = 0.f; md[j] = -FLT_MAX; }
  }
  #pragma unroll
  for (int grp = 0; grp < 3; ++grp) {
    float qx[4], qy[4], qz[4];
    #pragma unroll
    for (int q = 0; q < 4; ++q) {
      int j = PV + grp * 4 + q;
      int g = base + j * T_;
      if (g < N_) {
        const float* p = P + (size_t)g * 3;
        qx[q] = p[0]; qy[q] = p[1]; qz[q] = p[2];
        md[j] = __builtin_huge_valf();
      } else { qx[q] = qy[q] = qz[q] = 0.f; md[j] = -FLT_MAX; }
    }
    sX[grp][tid] = make_float4(qx[0], qx[1], qx[2], qx[3]);
    sY[grp][tid] = make_float4(qy[0], qy[1], qy[2], qy[3]);
    sZ[grp][tid] = make_float4(qz[0], qz[1], qz[2], qz[3]);
  }

  // FENCE: forbid store->load forwarding of the LDS staging (the r8 bug).
  // Any path from the init stores to a loop-body read crosses this clobber,
  // so reads must be real ds_reads and the arrays stay allocated in LDS.
  asm volatile("" ::: "memory");
  __syncthreads();                           // one-time; pins codegen shape

  float cx = P[0], cy = P[1], cz = P[2];     // initial center = point 0
  if (c == 0 && tid == 0) out[b * M_ + 0] = 0;

  for (int it = 1; it < M_; ++it) {
    asm volatile("" ::: "memory");           // belt-and-braces, zero cost

    // ---- distance + running-min + 4-chain argmax (j tracked, 5 bits) ----
    // No exclusion select: the chosen point's self-distance is exactly 0
    // (coords bit-exact), min(md,0)=0 never beats any positive min-dist, so
    // the argmax sequence matches the reference (proven r5-r8).
    float bv[4] = {-FLT_MAX, -FLT_MAX, -FLT_MAX, -FLT_MAX};
    int   bj[4] = {0x7FFF, 0x7FFF, 0x7FFF, 0x7FFF};

    #pragma unroll
    for (int j = 0; j < PV; ++j) {
      float dx = __fsub_rn(vx[j], cx);
      float dy = __fsub_rn(vy[j], cy);
      float dz = __fsub_rn(vz[j], cz);
      // numpy: ((dx*dx + dy*dy) + dz*dz), rn, no FMA contraction
      float d  = __fadd_rn(__fadd_rn(__fmul_rn(dx, dx), __fmul_rn(dy, dy)),
                           __fmul_rn(dz, dz));
      float m  = fminf(md[j], d);            // np.minimum
      md[j] = m;
      const int q = j & 3;
      bool take = m > bv[q];                 // ascending j: strict >
      bv[q] = take ? m : bv[q];
      bj[q] = take ? j : bj[q];
    }
    #pragma unroll
    for (int grp = 0; grp < 3; ++grp) {
      float4 qx = sX[grp][tid], qy = sY[grp][tid], qz = sZ[grp][tid];
      #pragma unroll
      for (int q4 = 0; q4 < 4; ++q4) {
        const int j = PV + grp * 4 + q4;
        float X = (q4 == 0) ? qx.x : (q4 == 1) ? qx.y : (q4 == 2) ? qx.z : qx.w;
        float Y = (q4 == 0) ? qy.x : (q4 == 1) ? qy.y : (q4 == 2) ? qy.z : qy.w;
        float Z = (q4 == 0) ? qz.x : (q4 == 1) ? qz.y : (q4 == 2) ? qz.z : qz.w;
        float dx = __fsub_rn(X, cx);
        float dy = __fsub_rn(Y, cy);
        float dz = __fsub_rn(Z, cz);
        float d  = __fadd_rn(__fadd_rn(__fmul_rn(dx, dx), __fmul_rn(dy, dy)),
                             __fmul_rn(dz, dz));
        float m  = fminf(md[j], d);
        md[j] = m;
        const int q = j & 3;
        bool take = m > bv[q];
        bv[q] = take ? m : bv[q];
        bj[q] = take ? j : bj[q];
      }
    }
    // merge 4 chains (tie -> smaller j = smaller global idx = first occurrence)
    float tv = bv[0]; int tj = bj[0];
    #pragma unroll
    for (int q = 1; q < 4; ++q) {
      bool take = (bv[q] > tv) || (bv[q] == tv && bj[q] < tj);
      tv = take ? bv[q] : tv;
      tj = take ? bj[q] : tj;
    }
    int ti = base + tj * T_;                 // reconstruct global idx once

    // ---- wave reduction (64 lanes) ----
    #pragma unroll
    for (int o = 32; o > 0; o >>= 1) {
      float ov = __shfl_xor(tv, o);
      int   oi = __shfl_xor(ti, o);
      bool take = (ov > tv) || (ov == tv && oi < ti);
      tv = take ? ov : tv;
      ti = take ? oi : ti;
    }

    // ---- publish this wave's candidate (one u64 tag, relaxed agent) ----
    // 128 slots per batch per parity: slot = c*16 + wave.
    unsigned long long* grp = tags + (((size_t)(b << 1) + (it & 1)) << 7);
    if (lane == 0) {
      unsigned long long tg =
          ((unsigned long long)__float_as_uint(tv) << 32) |
          ((unsigned long long)(unsigned)ti << 7) | (unsigned)it;
      __hip_atomic_store(grp + ((c << 4) | wave), tg,
                         __ATOMIC_RELAXED, __HIP_MEMORY_SCOPE_AGENT);
    }

    // ---- every wave polls all 128 slots (lane l -> slots l, l+64) ----
    unsigned long long t0 = 0, t1 = 0;
    {
      int sp = 0;
      for (;;) {
        t0 = __hip_atomic_load(grp + lane,      __ATOMIC_RELAXED, __HIP_MEMORY_SCOPE_AGENT);
        t1 = __hip_atomic_load(grp + lane + 64, __ATOMIC_RELAXED, __HIP_MEMORY_SCOPE_AGENT);
        bool ok = ((t0 & 127ull) == (unsigned long long)(unsigned)it) &&
                  ((t1 & 127ull) == (unsigned long long)(unsigned)it);
        if (__all(ok)) break;
        if (++sp > SPIN_CAP) break;          // wrong answer >> dead container
        __builtin_amdgcn_s_sleep(1);
      }
    }
    // merge the two slots, then 6-stage butterfly -> global winner (all lanes)
    float v0 = __uint_as_float((unsigned)(t0 >> 32));
    int   i0 = (int)((t0 >> 7) & 0x3FFFF);
    float v1 = __uint_as_float((unsigned)(t1 >> 32));
    int   i1 = (int)((t1 >> 7) & 0x3FFFF);
    bool tk = (v1 > v0) || (v1 == v0 && i1 < i0);
    float cv = tk ? v1 : v0;
    int   ci = tk ? i1 : i0;
    #pragma unroll
    for (int o = 32; o > 0; o >>= 1) {
      float ov = __shfl_xor(cv, o);
      int   oi = __shfl_xor(ci, o);
      bool take = (ov > cv) || (ov == cv && oi < ci);
      cv = take ? ov : cv;
      ci = take ? oi : ci;
    }

    if (c == 0 && tid == 0) out[b * M_ + it] = ci;   // fire-and-forget

    // winner coords: read-only P, XCD-L2-resident -> ~200cy broadcast load.
    const float* pw = P + (size_t)ci * 3;
    cx = pw[0]; cy = pw[1]; cz = pw[2];
  }
}

extern "C" void kernel_launch(void* const* d_in, const int* in_sizes, int n_in,
                              void* d_out, int out_size, void* d_ws, size_t ws_size,
                              hipStream_t stream) {
  const float*        pts  = (const float*)d_in[0];
  int*                out  = (int*)d_out;
  unsigned long long* tags = (unsigned long long*)d_ws;

  // zero tag slots each launch (tag 0 never matches it>=1); capture-safe
  hipMemsetAsync(d_ws, 0, (size_t)B_ * 2 * 128 * sizeof(unsigned long long), stream);

  // 144 KiB LDS/block -> 1 block/CU; grid == 256 == CU count -> co-resident.
  fps_kernel<<<dim3(B_ * BPB), dim3(T_), 0, stream>>>(pts, out, tags);
}

// Round 10
// 492.509 us; speedup vs baseline: 3.7947x; 2.4821x over previous
//
#include <hip/hip_runtime.h>
#include <cfloat>

// Farthest Point Sampling: B=32, N=200000, M=128.
// r7 champion topology (529us) EXACTLY: 8 blocks/batch x 1024 threads,
// 1 block/CU (LDS-forced), XCD-local batches, wave0 relay with 2 barriers,
// relaxed u64 tag protocol. This round: packed-f32 scan (v_pk_add/mul via
// <2 x float>), PT=26 as 13 pairs: 7 pairs in VGPRs + 6 pairs in LDS float4.
#define B_    32
#define N_    200000
#define M_    128
#define BPB   8                    // blocks per batch
#define T_    1024                 // threads per block
#define PT    26                   // points per thread (13 pairs)
#define NPAIR 13
#define PVP   7                    // pairs in VGPRs (j = 0..13)
#define CHUNK (T_ * PT)            // 26624 points per block; 8*26624 >= N

#define SPIN_CAP (1 << 20)         // safety valve: never hang the container

typedef float v2f __attribute__((ext_vector_type(2)));

__global__ __launch_bounds__(T_, 4)
void fps_kernel(const float* __restrict__ pts, int* __restrict__ out,
                unsigned long long* __restrict__ tags) {
#pragma clang fp contract(off)
  const int tid = threadIdx.x;
  const int bid = blockIdx.x;
  // XCD-local batches: blocks round-robin XCDs by bid&7 (measured m09).
  // All 8 blocks of a batch -> one XCD; the batch's 2.4MB of points fits that
  // XCD's 4MB L2 -> tag exchange AND coord fetches stay L2-local.
  const int xcd = bid & 7;
  const int sl8 = bid >> 3;                  // 0..31 within this XCD
  const int b   = ((sl8 >> 3) << 3) | xcd;   // batch (b&7 == xcd)
  const int c   = sl8 & 7;                   // chunk within batch
  const int wave = tid >> 6;
  const int lane = tid & 63;

  const float* __restrict__ P = pts + (size_t)b * (size_t)(N_ * 3);
  const int base = c * CHUNK + tid;          // this thread's j=0 global index

  // 3 arrays x [3][1024] float4 = 144 KiB -> exactly 1 block/CU.
  // sX[g][tid] holds x of points j = 14+4g .. 17+4g (thread-private column).
  __shared__ float4 sX[3][T_], sY[3][T_], sZ[3][T_];
  __shared__ float  sv[16];
  __shared__ int    si[16];
  __shared__ int    wfar;
  __shared__ float  wx, wy, wz;

  // ---- one-time load ----
  v2f x2[PVP], y2[PVP], z2[PVP], md2[NPAIR];
  #pragma unroll
  for (int p = 0; p < PVP; ++p) {
    const int j0 = 2 * p, j1 = 2 * p + 1;
    const int g0 = base + j0 * T_, g1 = base + j1 * T_;
    float m0, m1;
    if (g0 < N_) {
      const float* q = P + (size_t)g0 * 3;
      x2[p].x = q[0]; y2[p].x = q[1]; z2[p].x = q[2];
      m0 = __builtin_huge_valf();
    } else { x2[p].x = 0.f; y2[p].x = 0.f; z2[p].x = 0.f; m0 = -FLT_MAX; }
    if (g1 < N_) {
      const float* q = P + (size_t)g1 * 3;
      x2[p].y = q[0]; y2[p].y = q[1]; z2[p].y = q[2];
      m1 = __builtin_huge_valf();
    } else { x2[p].y = 0.f; y2[p].y = 0.f; z2[p].y = 0.f; m1 = -FLT_MAX; }
    md2[p].x = m0; md2[p].y = m1;
  }
  #pragma unroll
  for (int g = 0; g < 3; ++g) {
    float qx[4], qy[4], qz[4];
    #pragma unroll
    for (int q = 0; q < 4; ++q) {
      const int j = 14 + 4 * g + q;
      const int gg = base + j * T_;
      float m;
      if (gg < N_) {
        const float* pp = P + (size_t)gg * 3;
        qx[q] = pp[0]; qy[q] = pp[1]; qz[q] = pp[2];
        m = __builtin_huge_valf();
      } else { qx[q] = 0.f; qy[q] = 0.f; qz[q] = 0.f; m = -FLT_MAX; }
      const int pr = 7 + 2 * g + (q >> 1);   // pair index 7..12
      if ((q & 1) == 0) md2[pr].x = m; else md2[pr].y = m;
    }
    sX[g][tid] = make_float4(qx[0], qx[1], qx[2], qx[3]);
    sY[g][tid] = make_float4(qy[0], qy[1], qy[2], qy[3]);
    sZ[g][tid] = make_float4(qz[0], qz[1], qz[2], qz[3]);
  }

  float cx = P[0], cy = P[1], cz = P[2];     // initial center = point 0
  if (c == 0 && tid == 0) out[b * M_ + 0] = 0;

  for (int it = 1; it < M_; ++it) {
    // ---- packed distance + running-min + 2-parity-chain argmax ----
    // No exclusion select: the chosen point's self-distance is exactly 0
    // (coords bit-exact), min(md,0)=0 never beats any positive min-dist, so
    // the argmax sequence matches the reference (proven r5-r9).
    // Packed ops are per-component rn: bit-identical to scalar sequence;
    // fp contract(off) forbids pk_fma, preserving ((dx2+dy2)+dz2) rounding.
    const v2f C_x = {cx, cx}, C_y = {cy, cy}, C_z = {cz, cz};
    float bvE = -FLT_MAX, bvO = -FLT_MAX;    // even-j / odd-j chains
    int   bjE = 0x7FFF,   bjO = 0x7FFF;

    #pragma unroll
    for (int p = 0; p < PVP; ++p) {
      v2f dx = x2[p] - C_x;                  // v_pk_add (neg)
      v2f dy = y2[p] - C_y;
      v2f dz = z2[p] - C_z;
      v2f s  = (dx * dx + dy * dy) + dz * dz; // 3 pk_mul + 2 pk_add, no fma
      v2f mm = __builtin_elementwise_min(md2[p], s);  // np.minimum
      md2[p] = mm;
      bool tE = mm.x > bvE;                  // ascending j: strict >
      bvE = tE ? mm.x : bvE;
      bjE = tE ? 2 * p : bjE;
      bool tO = mm.y > bvO;
      bvO = tO ? mm.y : bvO;
      bjO = tO ? 2 * p + 1 : bjO;
    }
    #pragma unroll
    for (int g = 0; g < 3; ++g) {
      float4 qx = sX[g][tid], qy = sY[g][tid], qz = sZ[g][tid];
      #pragma unroll
      for (int h = 0; h < 2; ++h) {          // two pairs per float4 group
        const int p = 7 + 2 * g + h;         // pair index
        v2f X = (h == 0) ? (v2f){qx.x, qx.y} : (v2f){qx.z, qx.w};
        v2f Y = (h == 0) ? (v2f){qy.x, qy.y} : (v2f){qy.z, qy.w};
        v2f Z = (h == 0) ? (v2f){qz.x, qz.y} : (v2f){qz.z, qz.w};
        v2f dx = X - C_x;
        v2f dy = Y - C_y;
        v2f dz = Z - C_z;
        v2f s  = (dx * dx + dy * dy) + dz * dz;
        v2f mm = __builtin_elementwise_min(md2[p], s);
        md2[p] = mm;
        bool tE = mm.x > bvE;
        bvE = tE ? mm.x : bvE;
        bjE = tE ? 2 * p : bjE;
        bool tO = mm.y > bvO;
        bvO = tO ? mm.y : bvO;
        bjO = tO ? 2 * p + 1 : bjO;
      }
    }
    // merge parity chains (tie -> smaller j = smaller global idx)
    bool tk0 = (bvO > bvE) || (bvO == bvE && bjO < bjE);
    float tv = tk0 ? bvO : bvE;
    int   tj = tk0 ? bjO : bjE;
    int   ti = base + tj * T_;               // reconstruct global idx once

    // ---- wave reduction (64 lanes) ----
    #pragma unroll
    for (int o = 32; o > 0; o >>= 1) {
      float ov = __shfl_xor(tv, o);
      int   oi = __shfl_xor(ti, o);
      bool take = (ov > tv) || (ov == tv && oi < ti);
      tv = take ? ov : tv;
      ti = take ? oi : ti;
    }
    if (lane == 0) { sv[wave] = tv; si[wave] = ti; }
    __syncthreads();

    if (wave == 0) {
      // cross-wave reduce (16 entries)
      float v = (lane < 16) ? sv[lane] : -FLT_MAX;
      int   i = (lane < 16) ? si[lane] : 0x7FFFFFFF;
      #pragma unroll
      for (int o = 8; o > 0; o >>= 1) {
        float ov = __shfl_xor(v, o);
        int   oi = __shfl_xor(i, o);
        bool take = (ov > v) || (ov == v && oi < i);
        v = take ? ov : v;
        i = take ? oi : i;
      }
      // publish IMMEDIATELY: tag = (valbits<<32)|(idx<<7)|iter carries the
      // whole message in one atomic word -> RELAXED suffices, no buffer_inv.
      unsigned long long* grp = tags + (((b << 1) + (it & 1)) << 3);
      if (lane == 0) {
        unsigned long long tg =
            ((unsigned long long)__float_as_uint(v) << 32) |
            ((unsigned long long)(unsigned)i << 7) | (unsigned)it;
        __hip_atomic_store(grp + c, tg, __ATOMIC_RELAXED, __HIP_MEMORY_SCOPE_AGENT);
      }
      // poll the 8 block tags (lanes 0..7, relaxed, XCD-local L2 line)
      unsigned long long t = 0;
      if (lane < BPB) {
        int sp = 0;
        for (;;) {
          t = __hip_atomic_load(grp + lane, __ATOMIC_RELAXED, __HIP_MEMORY_SCOPE_AGENT);
          if ((t & 127ull) == (unsigned long long)(unsigned)it) break;
          if (++sp > SPIN_CAP) break;        // wrong answer >> dead container
          __builtin_amdgcn_s_sleep(1);
        }
      }
      float cv = (lane < BPB) ? __uint_as_float((unsigned)(t >> 32)) : -FLT_MAX;
      int   ci = (lane < BPB) ? (int)((t >> 7) & 0x3FFFF) : 0x7FFFFFFF;
      #pragma unroll
      for (int o = 4; o > 0; o >>= 1) {
        float ov = __shfl_xor(cv, o);
        int   oi = __shfl_xor(ci, o);
        bool take = (ov > cv) || (ov == cv && oi < ci);
        cv = take ? ov : cv;
        ci = take ? oi : ci;
      }
      if (lane == 0) {
        if (c == 0) out[b * M_ + it] = ci;   // fire-and-forget
        // winner coords: P is read-only (no coherence needed); batch data is
        // L2-resident on this XCD -> ~200cy. Off the publish critical path.
        const float* pw = P + (size_t)ci * 3;
        wfar = ci; wx = pw[0]; wy = pw[1]; wz = pw[2];
      }
    }
    __syncthreads();
    cx = wx; cy = wy; cz = wz; (void)wfar;
  }
}

extern "C" void kernel_launch(void* const* d_in, const int* in_sizes, int n_in,
                              void* d_out, int out_size, void* d_ws, size_t ws_size,
                              hipStream_t stream) {
  const float*        pts  = (const float*)d_in[0];
  int*                out  = (int*)d_out;
  unsigned long long* tags = (unsigned long long*)d_ws;

  // zero tag slots each launch (tag 0 never matches it>=1); capture-safe
  hipMemsetAsync(d_ws, 0, (size_t)B_ * 2 * BPB * sizeof(unsigned long long), stream);

  // 144 KiB LDS/block -> 1 block/CU; grid == 256 == CU count -> co-resident.
  fps_kernel<<<dim3(B_ * BPB), dim3(T_), 0, stream>>>(pts, out, tags);
}